// Round 11
// baseline (289.806 us; speedup 1.0000x reference)
//
#include <hip/hip_runtime.h>

#define B_ 4
#define T_ 2048
#define C_ 1024
#define H_ 16
#define D_ 64
#define EPS_ 1.1920929e-07f
#define LOG2E_ 1.4426950408889634f

typedef __attribute__((ext_vector_type(8))) short bf16x8;
typedef __attribute__((ext_vector_type(4))) float f32x4;
typedef __attribute__((ext_vector_type(16))) float f32x16;
typedef unsigned short u16;
typedef unsigned int u32;
typedef __attribute__((ext_vector_type(4))) u32 u32x4;

__device__ inline u16 f2bf(float f) {
  unsigned u = __float_as_uint(f);
  unsigned r = (u + 0x7fffu + ((u >> 16) & 1u)) >> 16;
  return (u16)r;
}

// async global->LDS, 16B per lane (dest = wave-uniform base + lane*16)
__device__ __forceinline__ void gload16(const void* g, void* l) {
  __builtin_amdgcn_global_load_lds(
      (__attribute__((address_space(1))) void*)g,
      (__attribute__((address_space(3))) void*)l, 16, 0, 0);
}

// ---------------- all f32->bf16 conversions in ONE launch ----------------
__global__ __launch_bounds__(256) void cvt_all(const float* __restrict__ x,
                                               const float* __restrict__ wq,
                                               const float* __restrict__ wk,
                                               const float* __restrict__ wv,
                                               const float* __restrict__ wo,
                                               u16* __restrict__ xb,
                                               u16* __restrict__ wqkv,
                                               u16* __restrict__ wob) {
  const int NXB = (int)((size_t)B_ * T_ * C_ / 1024);  // 8192
  const int WB = (C_ * C_) / 1024;                     // 1024
  const int bid = blockIdx.x;
  const float* src;
  u16* dst;
  int i;
  if (bid < NXB) {
    src = x; dst = xb; i = bid * 1024 + threadIdx.x * 4;
  } else {
    const int wb = bid - NXB;
    const int t = wb / WB;
    const int r = wb - t * WB;
    src = (t == 0) ? wq : (t == 1) ? wk : (t == 2) ? wv : wo;
    dst = (t == 3) ? wob : (wqkv + (size_t)t * (C_ * C_));
    i = r * 1024 + threadIdx.x * 4;
  }
  float4 v = *(const float4*)&src[i];
  ushort4 o;
  o.x = f2bf(v.x); o.y = f2bf(v.y); o.z = f2bf(v.z); o.w = f2bf(v.w);
  *(ushort4*)&dst[i] = o;
}

// ---------------- fused QKV GEMM: [Q|K|V] = X @ Wqkv^T + epilogues ----------------
// 128x256 tile, BK=64, 8 waves, dbuf LDS, one barrier/K-step.
// T2 LDS swizzle (rule #21 pairing): linear gload_lds dest + inverse-swizzled
// GLOBAL source col ((lane&7)^(lane>>3))*8 + XOR on ds_read (ko ^ (r&7)<<3).
// bx: 0..3 -> Q (rope+rms, *scale*log2e), 4..7 -> K, 8..11 -> V (transposed+slot-perm).
__global__ __launch_bounds__(512) void gemm_qkv(const u16* __restrict__ X,
                                                const u16* __restrict__ W,
                                                u16* __restrict__ qb,
                                                u16* __restrict__ kb,
                                                u16* __restrict__ vtb,
                                                const float* __restrict__ cs,
                                                const float* __restrict__ sn,
                                                int M, int K) {
  __shared__ short As[2][128 * 64];
  __shared__ short Bs[2][256 * 64];
  const int tid = threadIdx.x;
  const int lane = tid & 63;
  const int wid = tid >> 6;           // 0..7
  const int wm = wid >> 2, wn = wid & 3;
  const int bx = blockIdx.x, by = blockIdx.y;
  const int m0 = by * 128, n0 = bx * 256;
  const int w8 = wid * 8;
  const int lrow = lane >> 3;         // 0..7
  const int scol = ((lane & 7) ^ lrow) * 8;  // inverse-swizzled source col (u16)

  f32x4 acc[4][4];
#pragma unroll
  for (int mi = 0; mi < 4; ++mi)
#pragma unroll
    for (int ni = 0; ni < 4; ++ni)
      acc[mi][ni] = (f32x4){0.f, 0.f, 0.f, 0.f};

  const int r = lane & 15;
  const int quad = lane >> 4;
  const int rx = (r & 7) << 3;        // read-side XOR (u16 units)

  // prologue: stage tile 0 into buf 0
#pragma unroll
  for (int ra = 0; ra < 2; ++ra)
    gload16(&X[(size_t)(m0 + ra * 64 + w8 + lrow) * K + scol], &As[0][(ra * 64 + w8) * 64]);
#pragma unroll
  for (int rb = 0; rb < 4; ++rb)
    gload16(&W[(size_t)(n0 + rb * 64 + w8 + lrow) * K + scol], &Bs[0][(rb * 64 + w8) * 64]);
  __syncthreads();

#pragma unroll 2
  for (int it = 0; it < 16; ++it) {   // K = 1024 = 16 * 64
    const int cur = it & 1;
    const int kt = it * 64;
    if (it + 1 < 16) {                // stage next tile into alternate buffer
      const int nb = cur ^ 1;
#pragma unroll
      for (int ra = 0; ra < 2; ++ra)
        gload16(&X[(size_t)(m0 + ra * 64 + w8 + lrow) * K + kt + 64 + scol], &As[nb][(ra * 64 + w8) * 64]);
#pragma unroll
      for (int rb = 0; rb < 4; ++rb)
        gload16(&W[(size_t)(n0 + rb * 64 + w8 + lrow) * K + kt + 64 + scol], &Bs[nb][(rb * 64 + w8) * 64]);
    }
#pragma unroll
    for (int kc = 0; kc < 2; ++kc) {
      const int ko = (kc * 32 + quad * 8) ^ rx;   // swizzled read col
      bf16x8 a[4], b[4];
#pragma unroll
      for (int mi = 0; mi < 4; ++mi)
        a[mi] = *(const bf16x8*)&As[cur][(wm * 64 + mi * 16 + r) * 64 + ko];
#pragma unroll
      for (int ni = 0; ni < 4; ++ni)
        b[ni] = *(const bf16x8*)&Bs[cur][(wn * 64 + ni * 16 + r) * 64 + ko];
#pragma unroll
      for (int mi = 0; mi < 4; ++mi)
#pragma unroll
        for (int ni = 0; ni < 4; ++ni)
          acc[mi][ni] = __builtin_amdgcn_mfma_f32_16x16x32_bf16(a[mi], b[ni], acc[mi][ni], 0, 0, 0);
    }
    __syncthreads();                  // drains vmcnt -> staged tile visible
  }

  const int which = bx >> 2;                 // 0=Q 1=K 2=V
  const int c0 = (bx & 3) * 256 + wn * 64;   // column within tensor (one head/wave)

  if (which < 2) {
    u16* dst = (which == 0) ? qb : kb;
    // fused RoPE + RMSNorm; d = ni*16+r, pair (d,d+32) = (ni,ni+2) in-lane
#pragma unroll
    for (int mi = 0; mi < 4; ++mi)
#pragma unroll
      for (int j = 0; j < 4; ++j) {
        const int gr = m0 + wm * 64 + mi * 16 + quad * 4 + j;
        const int t = gr & (T_ - 1);
        float o[4];
#pragma unroll
        for (int ni = 0; ni < 2; ++ni) {
          const float c = cs[t * 32 + ni * 16 + r];
          const float s = sn[t * 32 + ni * 16 + r];
          const float x1 = acc[mi][ni][j], x2 = acc[mi][ni + 2][j];
          o[ni]     = x1 * c + x2 * s;
          o[ni + 2] = x2 * c - x1 * s;
        }
        float sq = o[0] * o[0] + o[1] * o[1] + o[2] * o[2] + o[3] * o[3];
        sq += __shfl_xor(sq, 1, 64);
        sq += __shfl_xor(sq, 2, 64);
        sq += __shfl_xor(sq, 4, 64);
        sq += __shfl_xor(sq, 8, 64);
        float rn = rsqrtf(sq * (1.0f / 64.0f) + EPS_);
        if (which == 0) rn *= 0.125f * LOG2E_;  // fold attn scale AND log2(e) into Q
#pragma unroll
        for (int ni = 0; ni < 4; ++ni)
          dst[(size_t)gr * C_ + c0 + ni * 16 + r] = f2bf(o[ni] * rn);
      }
  } else {
    // V: transposed + slot-permuted store. head h, d = ni*16+r.
    // key-in-tile = mi*16 + quad*4 + j -> slot = mi*16 + (j>>1)*8 + quad*2 + (j&1)
    const int h = (bx & 3) * 4 + wn;
    const int gr0 = m0 + wm * 64;
    const int bb = gr0 >> 11;         // batch (T_=2048)
    const int tbase = gr0 & (T_ - 1); // multiple of 64
#pragma unroll
    for (int ni = 0; ni < 4; ++ni) {
      const int d = ni * 16 + r;
      u16* rowp = &vtb[((size_t)((bb * H_ + h) * D_ + d)) * T_ + tbase];
#pragma unroll
      for (int mi = 0; mi < 4; ++mi) {
        u32 lo, hi2;
        asm("v_cvt_pk_bf16_f32 %0, %1, %2" : "=v"(lo) : "v"(acc[mi][ni][0]), "v"(acc[mi][ni][1]));
        asm("v_cvt_pk_bf16_f32 %0, %1, %2" : "=v"(hi2) : "v"(acc[mi][ni][2]), "v"(acc[mi][ni][3]));
        u16* p = rowp + mi * 16 + quad * 2;
        *(u32*)&p[0] = lo;
        *(u32*)&p[8] = hi2;
      }
    }
  }
}

// ---------------- output GEMM: out = Y @ Wo^T (fp32 out) ----------------
// 128x128 tile, 4 waves, 2-phase dbuf + T2 swizzle, LDS 64KB -> grid 8x64 =
// 512 blocks = 2 blocks/CU = 16 waves/CU (was 128x256, 256 blocks = 1/CU =
// 2 waves/SIMD -- occupancy-starved, barrier drain unhidden; R8 TLP lesson).
__global__ __launch_bounds__(256) void gemm_out(const u16* __restrict__ X,
                                                const u16* __restrict__ W,
                                                float* __restrict__ Y,
                                                int M, int N, int K) {
  __shared__ short As[2][128 * 64];
  __shared__ short Bs[2][128 * 64];
  const int tid = threadIdx.x;
  const int lane = tid & 63;
  const int wid = tid >> 6;           // 0..3
  const int wm = wid >> 1, wn = wid & 1;
  const int m0 = blockIdx.y * 128, n0 = blockIdx.x * 128;
  const int w8 = wid * 8;
  const int lrow = lane >> 3;
  const int scol = ((lane & 7) ^ lrow) * 8;

  f32x4 acc[4][4];
#pragma unroll
  for (int mi = 0; mi < 4; ++mi)
#pragma unroll
    for (int ni = 0; ni < 4; ++ni)
      acc[mi][ni] = (f32x4){0.f, 0.f, 0.f, 0.f};

  const int r = lane & 15;
  const int quad = lane >> 4;
  const int rx = (r & 7) << 3;

  // prologue: stage tile 0 (A: 4 rounds of 32 rows, B: 4 rounds)
#pragma unroll
  for (int ra = 0; ra < 4; ++ra)
    gload16(&X[(size_t)(m0 + ra * 32 + w8 + lrow) * K + scol], &As[0][(ra * 32 + w8) * 64]);
#pragma unroll
  for (int rb = 0; rb < 4; ++rb)
    gload16(&W[(size_t)(n0 + rb * 32 + w8 + lrow) * K + scol], &Bs[0][(rb * 32 + w8) * 64]);
  __syncthreads();

#pragma unroll 2
  for (int it = 0; it < 16; ++it) {
    const int cur = it & 1;
    const int kt = it * 64;
    if (it + 1 < 16) {
      const int nb = cur ^ 1;
#pragma unroll
      for (int ra = 0; ra < 4; ++ra)
        gload16(&X[(size_t)(m0 + ra * 32 + w8 + lrow) * K + kt + 64 + scol], &As[nb][(ra * 32 + w8) * 64]);
#pragma unroll
      for (int rb = 0; rb < 4; ++rb)
        gload16(&W[(size_t)(n0 + rb * 32 + w8 + lrow) * K + kt + 64 + scol], &Bs[nb][(rb * 32 + w8) * 64]);
    }
#pragma unroll
    for (int kc = 0; kc < 2; ++kc) {
      const int ko = (kc * 32 + quad * 8) ^ rx;
      bf16x8 a[4], b[4];
#pragma unroll
      for (int mi = 0; mi < 4; ++mi)
        a[mi] = *(const bf16x8*)&As[cur][(wm * 64 + mi * 16 + r) * 64 + ko];
#pragma unroll
      for (int ni = 0; ni < 4; ++ni)
        b[ni] = *(const bf16x8*)&Bs[cur][(wn * 64 + ni * 16 + r) * 64 + ko];
#pragma unroll
      for (int mi = 0; mi < 4; ++mi)
#pragma unroll
        for (int ni = 0; ni < 4; ++ni)
          acc[mi][ni] = __builtin_amdgcn_mfma_f32_16x16x32_bf16(a[mi], b[ni], acc[mi][ni], 0, 0, 0);
    }
    __syncthreads();
  }

#pragma unroll
  for (int mi = 0; mi < 4; ++mi)
#pragma unroll
    for (int ni = 0; ni < 4; ++ni) {
      const int gc = n0 + wn * 64 + ni * 16 + r;
#pragma unroll
      for (int j = 0; j < 4; ++j) {
        const int gr = m0 + wm * 64 + mi * 16 + quad * 4 + j;
        Y[(size_t)gr * N + gc] = acc[mi][ni][j];
      }
    }
}

// ---------------- MFMA flash attention, swapped-QK 32x32x16, in-register P ----------------
// R6 structure (32q/wave, 16 waves/CU) with dense+swizzled 32KB LDS (R10).
__global__ __launch_bounds__(256) void flash_mfma(const u16* __restrict__ Qb,
                                                  const u16* __restrict__ Kb,
                                                  const u16* __restrict__ Vtb,
                                                  u16* __restrict__ Yb) {
  __shared__ u16 sm[16384];  // 32768 B: Ks[2] @ 0/4096, Vt[2] @ 8192/12288
#define LSWZ(row, g) ((row) * 64 + (((g) ^ ((row) & 7)) * 8))
#define KSB(buf) ((buf) * 4096)
#define VTB(buf) (8192 + (buf) * 4096)
  const int tid = threadIdx.x;
  const int lane = tid & 63;
  const int w = tid >> 6;
  const int c = lane & 31;        // QK: query col; PV: d col
  const int hi = lane >> 5;
  const int bh = blockIdx.x, qt = blockIdx.y;
  const int b = bh >> 4, h = bh & 15;
  const int srow = lane;          // K staging row (key)
  const int vrow = tid >> 2;      // V staging d row 0..63
  const int vg = (tid & 3) * 2;   // V staging granule base (slot/8)

  const u16* kbase = Kb + ((size_t)(b * T_ + srow) * H_ + h) * D_ + w * 16;
  const u16* vbase = Vtb + ((size_t)(bh * 64 + vrow)) * T_ + (tid & 3) * 16;
  const int KSTRIDE = 64 * H_ * D_;  // u16 elems per 64-key tile

  // issue K/V tile-0 loads first (hide latency under Q staging)
  bf16x8 k0, k1, v0, v1;
  k0 = *(const bf16x8*)&kbase[0];
  k1 = *(const bf16x8*)&kbase[8];
  v0 = *(const bf16x8*)&vbase[0];
  v1 = *(const bf16x8*)&vbase[8];

  // stage Q tile (128 x 64) through the Ks buffers: 2 threads per row
  {
    const int row = tid >> 1, half = tid & 1;
    const size_t g = ((size_t)((b * T_ + qt * 128 + row) * H_ + h)) * D_ + half * 32;
    const int base = (row < 64) ? KSB(0) : KSB(1);
    const int r2 = row & 63;
#pragma unroll
    for (int j = 0; j < 4; ++j)
      *(bf16x8*)&sm[base + LSWZ(r2, half * 4 + j)] = *(const bf16x8*)&Qb[g + j * 8];
  }
  __syncthreads();
  // qf[ks]: B-frag, lane (hi,c) = Q[w*32+c][ks*16 + hi*8 .. +8]
  bf16x8 qf[4];
  {
    const int qr = w * 32 + c;
    const int base = (qr < 64) ? KSB(0) : KSB(1);
    const int r2 = qr & 63;
#pragma unroll
    for (int ks = 0; ks < 4; ++ks)
      qf[ks] = *(const bf16x8*)&sm[base + LSWZ(r2, ks * 2 + hi)];
  }
  __syncthreads();

  // write tile 0 to buf 0, prefetch tile 1
  *(bf16x8*)&sm[KSB(0) + LSWZ(srow, w * 2)]     = k0;
  *(bf16x8*)&sm[KSB(0) + LSWZ(srow, w * 2 + 1)] = k1;
  *(bf16x8*)&sm[VTB(0) + LSWZ(vrow, vg)]        = v0;
  *(bf16x8*)&sm[VTB(0) + LSWZ(vrow, vg + 1)]    = v1;
  k0 = *(const bf16x8*)&kbase[KSTRIDE];
  k1 = *(const bf16x8*)&kbase[KSTRIDE + 8];
  v0 = *(const bf16x8*)&vbase[64];
  v1 = *(const bf16x8*)&vbase[64 + 8];
  __syncthreads();

  f32x16 oacc[2], oacc_l;
  oacc[0] = (f32x16)(0.f);
  oacc[1] = (f32x16)(0.f);
  oacc_l  = (f32x16)(0.f);
  bf16x8 onesv;
#pragma unroll
  for (int i = 0; i < 8; ++i) onesv[i] = (short)0x3F80;  // bf16 1.0

  const int NT = T_ / 64;  // 32
#pragma unroll 2
  for (int t = 0; t < NT; ++t) {
    const int cur = t & 1;

    // QK^T: s[kt2] = K[kt2*32..+32] x Q  (rows=keys, cols=queries)
    f32x16 s0 = (f32x16)(0.f), s1 = (f32x16)(0.f);
    __builtin_amdgcn_s_setprio(1);
#pragma unroll
    for (int ks = 0; ks < 4; ++ks) {
      bf16x8 kf0 = *(const bf16x8*)&sm[KSB(cur) + LSWZ(c, ks * 2 + hi)];
      bf16x8 kf1 = *(const bf16x8*)&sm[KSB(cur) + LSWZ(32 + c, ks * 2 + hi)];
      s0 = __builtin_amdgcn_mfma_f32_32x32x16_bf16(kf0, qf[ks], s0, 0, 0, 0);
      s1 = __builtin_amdgcn_mfma_f32_32x32x16_bf16(kf1, qf[ks], s1, 0, 0, 0);
    }
    __builtin_amdgcn_s_setprio(0);

    // stage next tile into alternate buffer; prefetch tile t+2
    if (t + 1 < NT) {
      const int nxt = cur ^ 1;
      *(bf16x8*)&sm[KSB(nxt) + LSWZ(srow, w * 2)]     = k0;
      *(bf16x8*)&sm[KSB(nxt) + LSWZ(srow, w * 2 + 1)] = k1;
      *(bf16x8*)&sm[VTB(nxt) + LSWZ(vrow, vg)]        = v0;
      *(bf16x8*)&sm[VTB(nxt) + LSWZ(vrow, vg + 1)]    = v1;
      if (t + 2 < NT) {
        const int gk = (t + 2) * KSTRIDE;
        k0 = *(const bf16x8*)&kbase[gk];
        k1 = *(const bf16x8*)&kbase[gk + 8];
        const int gv = (t + 2) * 64;
        v0 = *(const bf16x8*)&vbase[gv];
        v1 = *(const bf16x8*)&vbase[gv + 8];
      }
    }

    // softmax: p = exp2(s) (scale+log2e folded into Q); pack pairs; swap halves.
    u32 wrd[2][4][2];
#pragma unroll
    for (int m = 0; m < 4; ++m)
#pragma unroll
      for (int p = 0; p < 2; ++p) {
        float a0 = __builtin_amdgcn_exp2f(s0[m * 4 + p * 2]);
        float a1 = __builtin_amdgcn_exp2f(s0[m * 4 + p * 2 + 1]);
        float b0 = __builtin_amdgcn_exp2f(s1[m * 4 + p * 2]);
        float b1 = __builtin_amdgcn_exp2f(s1[m * 4 + p * 2 + 1]);
        asm("v_cvt_pk_bf16_f32 %0, %1, %2" : "=v"(wrd[0][m][p]) : "v"(a0), "v"(a1));
        asm("v_cvt_pk_bf16_f32 %0, %1, %2" : "=v"(wrd[1][m][p]) : "v"(b0), "v"(b1));
      }
#pragma unroll
    for (int kt2 = 0; kt2 < 2; ++kt2)
#pragma unroll
      for (int m = 0; m < 4; ++m)
        asm("v_permlane32_swap_b32 %0, %1" : "+v"(wrd[kt2][m][0]), "+v"(wrd[kt2][m][1]));

    bf16x8 pa[4];
    pa[0] = __builtin_bit_cast(bf16x8, (u32x4){wrd[0][0][0], wrd[0][0][1], wrd[0][1][0], wrd[0][1][1]});
    pa[1] = __builtin_bit_cast(bf16x8, (u32x4){wrd[0][2][0], wrd[0][2][1], wrd[0][3][0], wrd[0][3][1]});
    pa[2] = __builtin_bit_cast(bf16x8, (u32x4){wrd[1][0][0], wrd[1][0][1], wrd[1][1][0], wrd[1][1][1]});
    pa[3] = __builtin_bit_cast(bf16x8, (u32x4){wrd[1][2][0], wrd[1][2][1], wrd[1][3][0], wrd[1][3][1]});

    // O += P @ V ; l += P @ ones (row-sum lands aligned with oacc rows)
    __builtin_amdgcn_s_setprio(1);
#pragma unroll
    for (int ks = 0; ks < 4; ++ks) {
      bf16x8 vf0 = *(const bf16x8*)&sm[VTB(cur) + LSWZ(c, ks * 2 + hi)];
      bf16x8 vf1 = *(const bf16x8*)&sm[VTB(cur) + LSWZ(32 + c, ks * 2 + hi)];
      oacc[0] = __builtin_amdgcn_mfma_f32_32x32x16_bf16(pa[ks], vf0, oacc[0], 0, 0, 0);
      oacc[1] = __builtin_amdgcn_mfma_f32_32x32x16_bf16(pa[ks], vf1, oacc[1], 0, 0, 0);
      oacc_l  = __builtin_amdgcn_mfma_f32_32x32x16_bf16(pa[ks], onesv, oacc_l, 0, 0, 0);
    }
    __builtin_amdgcn_s_setprio(0);
    __syncthreads();
  }

  // epilogue: inv = 1/l, perfectly aligned with O rows -- no shuffles
#pragma unroll
  for (int v = 0; v < 16; ++v) {
    const float inv = 1.0f / oacc_l[v];
    const int q = (v & 3) + 8 * (v >> 2) + 4 * hi;
    const int tq = qt * 128 + w * 32 + q;
    const size_t gbase = ((size_t)((b * T_ + tq) * H_ + h)) * D_;
    Yb[gbase + c]      = f2bf(oacc[0][v] * inv);
    Yb[gbase + 32 + c] = f2bf(oacc[1][v] * inv);
  }
#undef LSWZ
#undef KSB
#undef VTB
}

extern "C" void kernel_launch(void* const* d_in, const int* in_sizes, int n_in,
                              void* d_out, int out_size, void* d_ws, size_t ws_size,
                              hipStream_t stream) {
  const float* x    = (const float*)d_in[0];
  const float* cosb = (const float*)d_in[1];
  const float* sinb = (const float*)d_in[2];
  const float* Wq   = (const float*)d_in[3];
  const float* Wk   = (const float*)d_in[4];
  const float* Wv   = (const float*)d_in[5];
  const float* Wo   = (const float*)d_in[6];
  float* out = (float*)d_out;

  const size_t NE = (size_t)B_ * T_ * C_;  // 8M elements
  const int CC = C_ * C_;                  // 1M elements
  // workspace (~72 MB): xb,qb,kb,vtb bf16 (64 MB) + wqkv (6 MB) + wob (2 MB)
  u16* xb   = (u16*)d_ws;
  u16* qb   = xb + NE;
  u16* kb   = qb + NE;
  u16* vtb  = kb + NE;   // V transposed + slot-permuted: [(b*H+h)*D + d][T]
  u16* wqkv = vtb + NE;
  u16* wob  = wqkv + 3 * (size_t)CC;
  u16* yb   = xb;  // xb dead after QKV GEMM; reuse for attention output

  const int M = B_ * T_;  // 8192

  const int NXB = (int)(NE / 1024);          // 8192
  const int NWB = 4 * (CC / 1024);           // 4096
  cvt_all<<<NXB + NWB, 256, 0, stream>>>(x, Wq, Wk, Wv, Wo, xb, wqkv, wob);

  dim3 qg(12, M / 128), gb(512);
  gemm_qkv<<<qg, gb, 0, stream>>>(xb, wqkv, qb, kb, vtb, cosb, sinb, M, C_);

  dim3 fg(B_ * H_, T_ / 128);
  flash_mfma<<<fg, 256, 0, stream>>>(qb, kb, vtb, yb);

  dim3 og(C_ / 128, M / 128);
  gemm_out<<<og, dim3(256), 0, stream>>>(yb, wob, out, M, C_, C_);
}

// Round 12
// 287.225 us; speedup vs baseline: 1.0090x; 1.0090x over previous
//
#include <hip/hip_runtime.h>

#define B_ 4
#define T_ 2048
#define C_ 1024
#define H_ 16
#define D_ 64
#define EPS_ 1.1920929e-07f
#define LOG2E_ 1.4426950408889634f

typedef __attribute__((ext_vector_type(8))) short bf16x8;
typedef __attribute__((ext_vector_type(4))) float f32x4;
typedef __attribute__((ext_vector_type(16))) float f32x16;
typedef unsigned short u16;
typedef unsigned int u32;
typedef __attribute__((ext_vector_type(4))) u32 u32x4;

__device__ inline u16 f2bf(float f) {
  unsigned u = __float_as_uint(f);
  unsigned r = (u + 0x7fffu + ((u >> 16) & 1u)) >> 16;
  return (u16)r;
}

// async global->LDS, 16B per lane (dest = wave-uniform base + lane*16)
__device__ __forceinline__ void gload16(const void* g, void* l) {
  __builtin_amdgcn_global_load_lds(
      (__attribute__((address_space(1))) void*)g,
      (__attribute__((address_space(3))) void*)l, 16, 0, 0);
}

// ---------------- all f32->bf16 conversions in ONE launch ----------------
__global__ __launch_bounds__(256) void cvt_all(const float* __restrict__ x,
                                               const float* __restrict__ wq,
                                               const float* __restrict__ wk,
                                               const float* __restrict__ wv,
                                               const float* __restrict__ wo,
                                               u16* __restrict__ xb,
                                               u16* __restrict__ wqkv,
                                               u16* __restrict__ wob) {
  const int NXB = (int)((size_t)B_ * T_ * C_ / 1024);  // 8192
  const int WB = (C_ * C_) / 1024;                     // 1024
  const int bid = blockIdx.x;
  const float* src;
  u16* dst;
  int i;
  if (bid < NXB) {
    src = x; dst = xb; i = bid * 1024 + threadIdx.x * 4;
  } else {
    const int wb = bid - NXB;
    const int t = wb / WB;
    const int r = wb - t * WB;
    src = (t == 0) ? wq : (t == 1) ? wk : (t == 2) ? wv : wo;
    dst = (t == 3) ? wob : (wqkv + (size_t)t * (C_ * C_));
    i = r * 1024 + threadIdx.x * 4;
  }
  float4 v = *(const float4*)&src[i];
  ushort4 o;
  o.x = f2bf(v.x); o.y = f2bf(v.y); o.z = f2bf(v.z); o.w = f2bf(v.w);
  *(ushort4*)&dst[i] = o;
}

// ---------------- fused QKV GEMM: [Q|K|V] = X @ Wqkv^T + epilogues ----------------
// 128x256 tile, BK=64, 8 waves, dbuf LDS, one barrier/K-step.
// T2 LDS swizzle (rule #21 pairing): linear gload_lds dest + inverse-swizzled
// GLOBAL source col ((lane&7)^(lane>>3))*8 + XOR on ds_read (ko ^ (r&7)<<3).
// bx: 0..3 -> Q (rope+rms, *scale*log2e), 4..7 -> K, 8..11 -> V (transposed+slot-perm).
__global__ __launch_bounds__(512) void gemm_qkv(const u16* __restrict__ X,
                                                const u16* __restrict__ W,
                                                u16* __restrict__ qb,
                                                u16* __restrict__ kb,
                                                u16* __restrict__ vtb,
                                                const float* __restrict__ cs,
                                                const float* __restrict__ sn,
                                                int M, int K) {
  __shared__ short As[2][128 * 64];
  __shared__ short Bs[2][256 * 64];
  const int tid = threadIdx.x;
  const int lane = tid & 63;
  const int wid = tid >> 6;           // 0..7
  const int wm = wid >> 2, wn = wid & 3;
  const int bx = blockIdx.x, by = blockIdx.y;
  const int m0 = by * 128, n0 = bx * 256;
  const int w8 = wid * 8;
  const int lrow = lane >> 3;         // 0..7
  const int scol = ((lane & 7) ^ lrow) * 8;  // inverse-swizzled source col (u16)

  f32x4 acc[4][4];
#pragma unroll
  for (int mi = 0; mi < 4; ++mi)
#pragma unroll
    for (int ni = 0; ni < 4; ++ni)
      acc[mi][ni] = (f32x4){0.f, 0.f, 0.f, 0.f};

  const int r = lane & 15;
  const int quad = lane >> 4;
  const int rx = (r & 7) << 3;        // read-side XOR (u16 units)

  // prologue: stage tile 0 into buf 0
#pragma unroll
  for (int ra = 0; ra < 2; ++ra)
    gload16(&X[(size_t)(m0 + ra * 64 + w8 + lrow) * K + scol], &As[0][(ra * 64 + w8) * 64]);
#pragma unroll
  for (int rb = 0; rb < 4; ++rb)
    gload16(&W[(size_t)(n0 + rb * 64 + w8 + lrow) * K + scol], &Bs[0][(rb * 64 + w8) * 64]);
  __syncthreads();

#pragma unroll 2
  for (int it = 0; it < 16; ++it) {   // K = 1024 = 16 * 64
    const int cur = it & 1;
    const int kt = it * 64;
    if (it + 1 < 16) {                // stage next tile into alternate buffer
      const int nb = cur ^ 1;
#pragma unroll
      for (int ra = 0; ra < 2; ++ra)
        gload16(&X[(size_t)(m0 + ra * 64 + w8 + lrow) * K + kt + 64 + scol], &As[nb][(ra * 64 + w8) * 64]);
#pragma unroll
      for (int rb = 0; rb < 4; ++rb)
        gload16(&W[(size_t)(n0 + rb * 64 + w8 + lrow) * K + kt + 64 + scol], &Bs[nb][(rb * 64 + w8) * 64]);
    }
#pragma unroll
    for (int kc = 0; kc < 2; ++kc) {
      const int ko = (kc * 32 + quad * 8) ^ rx;   // swizzled read col
      bf16x8 a[4], b[4];
#pragma unroll
      for (int mi = 0; mi < 4; ++mi)
        a[mi] = *(const bf16x8*)&As[cur][(wm * 64 + mi * 16 + r) * 64 + ko];
#pragma unroll
      for (int ni = 0; ni < 4; ++ni)
        b[ni] = *(const bf16x8*)&Bs[cur][(wn * 64 + ni * 16 + r) * 64 + ko];
#pragma unroll
      for (int mi = 0; mi < 4; ++mi)
#pragma unroll
        for (int ni = 0; ni < 4; ++ni)
          acc[mi][ni] = __builtin_amdgcn_mfma_f32_16x16x32_bf16(a[mi], b[ni], acc[mi][ni], 0, 0, 0);
    }
    __syncthreads();                  // drains vmcnt -> staged tile visible
  }

  const int which = bx >> 2;                 // 0=Q 1=K 2=V
  const int c0 = (bx & 3) * 256 + wn * 64;   // column within tensor (one head/wave)

  if (which < 2) {
    u16* dst = (which == 0) ? qb : kb;
    // fused RoPE + RMSNorm; d = ni*16+r, pair (d,d+32) = (ni,ni+2) in-lane
#pragma unroll
    for (int mi = 0; mi < 4; ++mi)
#pragma unroll
      for (int j = 0; j < 4; ++j) {
        const int gr = m0 + wm * 64 + mi * 16 + quad * 4 + j;
        const int t = gr & (T_ - 1);
        float o[4];
#pragma unroll
        for (int ni = 0; ni < 2; ++ni) {
          const float c = cs[t * 32 + ni * 16 + r];
          const float s = sn[t * 32 + ni * 16 + r];
          const float x1 = acc[mi][ni][j], x2 = acc[mi][ni + 2][j];
          o[ni]     = x1 * c + x2 * s;
          o[ni + 2] = x2 * c - x1 * s;
        }
        float sq = o[0] * o[0] + o[1] * o[1] + o[2] * o[2] + o[3] * o[3];
        sq += __shfl_xor(sq, 1, 64);
        sq += __shfl_xor(sq, 2, 64);
        sq += __shfl_xor(sq, 4, 64);
        sq += __shfl_xor(sq, 8, 64);
        float rn = rsqrtf(sq * (1.0f / 64.0f) + EPS_);
        if (which == 0) rn *= 0.125f * LOG2E_;  // fold attn scale AND log2(e) into Q
#pragma unroll
        for (int ni = 0; ni < 4; ++ni)
          dst[(size_t)gr * C_ + c0 + ni * 16 + r] = f2bf(o[ni] * rn);
      }
  } else {
    // V: transposed + slot-permuted store. head h, d = ni*16+r.
    // key-in-tile = mi*16 + quad*4 + j -> slot = mi*16 + (j>>1)*8 + quad*2 + (j&1)
    const int h = (bx & 3) * 4 + wn;
    const int gr0 = m0 + wm * 64;
    const int bb = gr0 >> 11;         // batch (T_=2048)
    const int tbase = gr0 & (T_ - 1); // multiple of 64
#pragma unroll
    for (int ni = 0; ni < 4; ++ni) {
      const int d = ni * 16 + r;
      u16* rowp = &vtb[((size_t)((bb * H_ + h) * D_ + d)) * T_ + tbase];
#pragma unroll
      for (int mi = 0; mi < 4; ++mi) {
        u32 lo, hi2;
        asm("v_cvt_pk_bf16_f32 %0, %1, %2" : "=v"(lo) : "v"(acc[mi][ni][0]), "v"(acc[mi][ni][1]));
        asm("v_cvt_pk_bf16_f32 %0, %1, %2" : "=v"(hi2) : "v"(acc[mi][ni][2]), "v"(acc[mi][ni][3]));
        u16* p = rowp + mi * 16 + quad * 2;
        *(u32*)&p[0] = lo;
        *(u32*)&p[8] = hi2;
      }
    }
  }
}

// ---------------- output GEMM: out = Y @ Wo^T (fp32 out) ----------------
// 128x128 tile, 4 waves, 2-phase dbuf + T2 swizzle, grid 8x64 = 512 blocks.
__global__ __launch_bounds__(256) void gemm_out(const u16* __restrict__ X,
                                                const u16* __restrict__ W,
                                                float* __restrict__ Y,
                                                int M, int N, int K) {
  __shared__ short As[2][128 * 64];
  __shared__ short Bs[2][128 * 64];
  const int tid = threadIdx.x;
  const int lane = tid & 63;
  const int wid = tid >> 6;           // 0..3
  const int wm = wid >> 1, wn = wid & 1;
  const int m0 = blockIdx.y * 128, n0 = blockIdx.x * 128;
  const int w8 = wid * 8;
  const int lrow = lane >> 3;
  const int scol = ((lane & 7) ^ lrow) * 8;

  f32x4 acc[4][4];
#pragma unroll
  for (int mi = 0; mi < 4; ++mi)
#pragma unroll
    for (int ni = 0; ni < 4; ++ni)
      acc[mi][ni] = (f32x4){0.f, 0.f, 0.f, 0.f};

  const int r = lane & 15;
  const int quad = lane >> 4;
  const int rx = (r & 7) << 3;

  // prologue: stage tile 0 (A: 4 rounds of 32 rows, B: 4 rounds)
#pragma unroll
  for (int ra = 0; ra < 4; ++ra)
    gload16(&X[(size_t)(m0 + ra * 32 + w8 + lrow) * K + scol], &As[0][(ra * 32 + w8) * 64]);
#pragma unroll
  for (int rb = 0; rb < 4; ++rb)
    gload16(&W[(size_t)(n0 + rb * 32 + w8 + lrow) * K + scol], &Bs[0][(rb * 32 + w8) * 64]);
  __syncthreads();

#pragma unroll 2
  for (int it = 0; it < 16; ++it) {
    const int cur = it & 1;
    const int kt = it * 64;
    if (it + 1 < 16) {
      const int nb = cur ^ 1;
#pragma unroll
      for (int ra = 0; ra < 4; ++ra)
        gload16(&X[(size_t)(m0 + ra * 32 + w8 + lrow) * K + kt + 64 + scol], &As[nb][(ra * 32 + w8) * 64]);
#pragma unroll
      for (int rb = 0; rb < 4; ++rb)
        gload16(&W[(size_t)(n0 + rb * 32 + w8 + lrow) * K + kt + 64 + scol], &Bs[nb][(rb * 32 + w8) * 64]);
    }
#pragma unroll
    for (int kc = 0; kc < 2; ++kc) {
      const int ko = (kc * 32 + quad * 8) ^ rx;
      bf16x8 a[4], b[4];
#pragma unroll
      for (int mi = 0; mi < 4; ++mi)
        a[mi] = *(const bf16x8*)&As[cur][(wm * 64 + mi * 16 + r) * 64 + ko];
#pragma unroll
      for (int ni = 0; ni < 4; ++ni)
        b[ni] = *(const bf16x8*)&Bs[cur][(wn * 64 + ni * 16 + r) * 64 + ko];
#pragma unroll
      for (int mi = 0; mi < 4; ++mi)
#pragma unroll
        for (int ni = 0; ni < 4; ++ni)
          acc[mi][ni] = __builtin_amdgcn_mfma_f32_16x16x32_bf16(a[mi], b[ni], acc[mi][ni], 0, 0, 0);
    }
    __syncthreads();
  }

#pragma unroll
  for (int mi = 0; mi < 4; ++mi)
#pragma unroll
    for (int ni = 0; ni < 4; ++ni) {
      const int gc = n0 + wn * 64 + ni * 16 + r;
#pragma unroll
      for (int j = 0; j < 4; ++j) {
        const int gr = m0 + wm * 64 + mi * 16 + quad * 4 + j;
        Y[(size_t)gr * N + gc] = acc[mi][ni][j];
      }
    }
}

// ---------------- MFMA flash attention, swapped-QK 32x32x16, in-register P ----------------
// R6 structure (32q/wave, 16 waves/CU) with dense+swizzled 32KB LDS (R10),
// plus zro-C trick: first QK MFMA takes a held zero C-operand, deleting the
// 32 v_mov s-init per tile (verified correct in R8's passing kernel).
__global__ __launch_bounds__(256) void flash_mfma(const u16* __restrict__ Qb,
                                                  const u16* __restrict__ Kb,
                                                  const u16* __restrict__ Vtb,
                                                  u16* __restrict__ Yb) {
  __shared__ u16 sm[16384];  // 32768 B: Ks[2] @ 0/4096, Vt[2] @ 8192/12288
#define LSWZ(row, g) ((row) * 64 + (((g) ^ ((row) & 7)) * 8))
#define KSB(buf) ((buf) * 4096)
#define VTB(buf) (8192 + (buf) * 4096)
  const int tid = threadIdx.x;
  const int lane = tid & 63;
  const int w = tid >> 6;
  const int c = lane & 31;        // QK: query col; PV: d col
  const int hi = lane >> 5;
  const int bh = blockIdx.x, qt = blockIdx.y;
  const int b = bh >> 4, h = bh & 15;
  const int srow = lane;          // K staging row (key)
  const int vrow = tid >> 2;      // V staging d row 0..63
  const int vg = (tid & 3) * 2;   // V staging granule base (slot/8)

  const u16* kbase = Kb + ((size_t)(b * T_ + srow) * H_ + h) * D_ + w * 16;
  const u16* vbase = Vtb + ((size_t)(bh * 64 + vrow)) * T_ + (tid & 3) * 16;
  const int KSTRIDE = 64 * H_ * D_;  // u16 elems per 64-key tile

  // issue K/V tile-0 loads first (hide latency under Q staging)
  bf16x8 k0, k1, v0, v1;
  k0 = *(const bf16x8*)&kbase[0];
  k1 = *(const bf16x8*)&kbase[8];
  v0 = *(const bf16x8*)&vbase[0];
  v1 = *(const bf16x8*)&vbase[8];

  // stage Q tile (128 x 64) through the Ks buffers: 2 threads per row
  {
    const int row = tid >> 1, half = tid & 1;
    const size_t g = ((size_t)((b * T_ + qt * 128 + row) * H_ + h)) * D_ + half * 32;
    const int base = (row < 64) ? KSB(0) : KSB(1);
    const int r2 = row & 63;
#pragma unroll
    for (int j = 0; j < 4; ++j)
      *(bf16x8*)&sm[base + LSWZ(r2, half * 4 + j)] = *(const bf16x8*)&Qb[g + j * 8];
  }
  __syncthreads();
  // qf[ks]: B-frag, lane (hi,c) = Q[w*32+c][ks*16 + hi*8 .. +8]
  bf16x8 qf[4];
  {
    const int qr = w * 32 + c;
    const int base = (qr < 64) ? KSB(0) : KSB(1);
    const int r2 = qr & 63;
#pragma unroll
    for (int ks = 0; ks < 4; ++ks)
      qf[ks] = *(const bf16x8*)&sm[base + LSWZ(r2, ks * 2 + hi)];
  }
  __syncthreads();

  // write tile 0 to buf 0, prefetch tile 1
  *(bf16x8*)&sm[KSB(0) + LSWZ(srow, w * 2)]     = k0;
  *(bf16x8*)&sm[KSB(0) + LSWZ(srow, w * 2 + 1)] = k1;
  *(bf16x8*)&sm[VTB(0) + LSWZ(vrow, vg)]        = v0;
  *(bf16x8*)&sm[VTB(0) + LSWZ(vrow, vg + 1)]    = v1;
  k0 = *(const bf16x8*)&kbase[KSTRIDE];
  k1 = *(const bf16x8*)&kbase[KSTRIDE + 8];
  v0 = *(const bf16x8*)&vbase[64];
  v1 = *(const bf16x8*)&vbase[64 + 8];
  __syncthreads();

  f32x16 oacc[2], oacc_l;
  oacc[0] = (f32x16)(0.f);
  oacc[1] = (f32x16)(0.f);
  oacc_l  = (f32x16)(0.f);
  const f32x16 zro = (f32x16)(0.f);  // held zeros: C-operand of first QK MFMA
  bf16x8 onesv;
#pragma unroll
  for (int i = 0; i < 8; ++i) onesv[i] = (short)0x3F80;  // bf16 1.0

  const int NT = T_ / 64;  // 32
#pragma unroll 2
  for (int t = 0; t < NT; ++t) {
    const int cur = t & 1;

    // QK^T: s[kt2] = K[kt2*32..+32] x Q  (rows=keys, cols=queries)
    // first ks uses zro as C (no per-tile s-init movs)
    f32x16 s0, s1;
    __builtin_amdgcn_s_setprio(1);
    {
      bf16x8 kf0 = *(const bf16x8*)&sm[KSB(cur) + LSWZ(c, hi)];
      bf16x8 kf1 = *(const bf16x8*)&sm[KSB(cur) + LSWZ(32 + c, hi)];
      s0 = __builtin_amdgcn_mfma_f32_32x32x16_bf16(kf0, qf[0], zro, 0, 0, 0);
      s1 = __builtin_amdgcn_mfma_f32_32x32x16_bf16(kf1, qf[0], zro, 0, 0, 0);
    }
#pragma unroll
    for (int ks = 1; ks < 4; ++ks) {
      bf16x8 kf0 = *(const bf16x8*)&sm[KSB(cur) + LSWZ(c, ks * 2 + hi)];
      bf16x8 kf1 = *(const bf16x8*)&sm[KSB(cur) + LSWZ(32 + c, ks * 2 + hi)];
      s0 = __builtin_amdgcn_mfma_f32_32x32x16_bf16(kf0, qf[ks], s0, 0, 0, 0);
      s1 = __builtin_amdgcn_mfma_f32_32x32x16_bf16(kf1, qf[ks], s1, 0, 0, 0);
    }
    __builtin_amdgcn_s_setprio(0);

    // stage next tile into alternate buffer; prefetch tile t+2
    if (t + 1 < NT) {
      const int nxt = cur ^ 1;
      *(bf16x8*)&sm[KSB(nxt) + LSWZ(srow, w * 2)]     = k0;
      *(bf16x8*)&sm[KSB(nxt) + LSWZ(srow, w * 2 + 1)] = k1;
      *(bf16x8*)&sm[VTB(nxt) + LSWZ(vrow, vg)]        = v0;
      *(bf16x8*)&sm[VTB(nxt) + LSWZ(vrow, vg + 1)]    = v1;
      if (t + 2 < NT) {
        const int gk = (t + 2) * KSTRIDE;
        k0 = *(const bf16x8*)&kbase[gk];
        k1 = *(const bf16x8*)&kbase[gk + 8];
        const int gv = (t + 2) * 64;
        v0 = *(const bf16x8*)&vbase[gv];
        v1 = *(const bf16x8*)&vbase[gv + 8];
      }
    }

    // softmax: p = exp2(s) (scale+log2e folded into Q); pack pairs; swap halves.
    u32 wrd[2][4][2];
#pragma unroll
    for (int m = 0; m < 4; ++m)
#pragma unroll
      for (int p = 0; p < 2; ++p) {
        float a0 = __builtin_amdgcn_exp2f(s0[m * 4 + p * 2]);
        float a1 = __builtin_amdgcn_exp2f(s0[m * 4 + p * 2 + 1]);
        float b0 = __builtin_amdgcn_exp2f(s1[m * 4 + p * 2]);
        float b1 = __builtin_amdgcn_exp2f(s1[m * 4 + p * 2 + 1]);
        asm("v_cvt_pk_bf16_f32 %0, %1, %2" : "=v"(wrd[0][m][p]) : "v"(a0), "v"(a1));
        asm("v_cvt_pk_bf16_f32 %0, %1, %2" : "=v"(wrd[1][m][p]) : "v"(b0), "v"(b1));
      }
#pragma unroll
    for (int kt2 = 0; kt2 < 2; ++kt2)
#pragma unroll
      for (int m = 0; m < 4; ++m)
        asm("v_permlane32_swap_b32 %0, %1" : "+v"(wrd[kt2][m][0]), "+v"(wrd[kt2][m][1]));

    bf16x8 pa[4];
    pa[0] = __builtin_bit_cast(bf16x8, (u32x4){wrd[0][0][0], wrd[0][0][1], wrd[0][1][0], wrd[0][1][1]});
    pa[1] = __builtin_bit_cast(bf16x8, (u32x4){wrd[0][2][0], wrd[0][2][1], wrd[0][3][0], wrd[0][3][1]});
    pa[2] = __builtin_bit_cast(bf16x8, (u32x4){wrd[1][0][0], wrd[1][0][1], wrd[1][1][0], wrd[1][1][1]});
    pa[3] = __builtin_bit_cast(bf16x8, (u32x4){wrd[1][2][0], wrd[1][2][1], wrd[1][3][0], wrd[1][3][1]});

    // O += P @ V ; l += P @ ones (row-sum lands aligned with oacc rows)
    __builtin_amdgcn_s_setprio(1);
#pragma unroll
    for (int ks = 0; ks < 4; ++ks) {
      bf16x8 vf0 = *(const bf16x8*)&sm[VTB(cur) + LSWZ(c, ks * 2 + hi)];
      bf16x8 vf1 = *(const bf16x8*)&sm[VTB(cur) + LSWZ(32 + c, ks * 2 + hi)];
      oacc[0] = __builtin_amdgcn_mfma_f32_32x32x16_bf16(pa[ks], vf0, oacc[0], 0, 0, 0);
      oacc[1] = __builtin_amdgcn_mfma_f32_32x32x16_bf16(pa[ks], vf1, oacc[1], 0, 0, 0);
      oacc_l  = __builtin_amdgcn_mfma_f32_32x32x16_bf16(pa[ks], onesv, oacc_l, 0, 0, 0);
    }
    __builtin_amdgcn_s_setprio(0);
    __syncthreads();
  }

  // epilogue: inv = 1/l, perfectly aligned with O rows -- no shuffles
#pragma unroll
  for (int v = 0; v < 16; ++v) {
    const float inv = 1.0f / oacc_l[v];
    const int q = (v & 3) + 8 * (v >> 2) + 4 * hi;
    const int tq = qt * 128 + w * 32 + q;
    const size_t gbase = ((size_t)((b * T_ + tq) * H_ + h)) * D_;
    Yb[gbase + c]      = f2bf(oacc[0][v] * inv);
    Yb[gbase + 32 + c] = f2bf(oacc[1][v] * inv);
  }
#undef LSWZ
#undef KSB
#undef VTB
}

extern "C" void kernel_launch(void* const* d_in, const int* in_sizes, int n_in,
                              void* d_out, int out_size, void* d_ws, size_t ws_size,
                              hipStream_t stream) {
  const float* x    = (const float*)d_in[0];
  const float* cosb = (const float*)d_in[1];
  const float* sinb = (const float*)d_in[2];
  const float* Wq   = (const float*)d_in[3];
  const float* Wk   = (const float*)d_in[4];
  const float* Wv   = (const float*)d_in[5];
  const float* Wo   = (const float*)d_in[6];
  float* out = (float*)d_out;

  const size_t NE = (size_t)B_ * T_ * C_;  // 8M elements
  const int CC = C_ * C_;                  // 1M elements
  // workspace (~72 MB): xb,qb,kb,vtb bf16 (64 MB) + wqkv (6 MB) + wob (2 MB)
  u16* xb   = (u16*)d_ws;
  u16* qb   = xb + NE;
  u16* kb   = qb + NE;
  u16* vtb  = kb + NE;   // V transposed + slot-permuted: [(b*H+h)*D + d][T]
  u16* wqkv = vtb + NE;
  u16* wob  = wqkv + 3 * (size_t)CC;
  u16* yb   = xb;  // xb dead after QKV GEMM; reuse for attention output

  const int M = B_ * T_;  // 8192

  const int NXB = (int)(NE / 1024);          // 8192
  const int NWB = 4 * (CC / 1024);           // 4096
  cvt_all<<<NXB + NWB, 256, 0, stream>>>(x, Wq, Wk, Wv, Wo, xb, wqkv, wob);

  dim3 qg(12, M / 128), gb(512);
  gemm_qkv<<<qg, gb, 0, stream>>>(xb, wqkv, qb, kb, vtb, cosb, sinb, M, C_);

  dim3 fg(B_ * H_, T_ / 128);
  flash_mfma<<<fg, 256, 0, stream>>>(qb, kb, vtb, yb);

  dim3 og(C_ / 128, M / 128);
  gemm_out<<<og, dim3(256), 0, stream>>>(yb, wob, out, M, C_, C_);
}